// Round 1
// baseline (1159.605 us; speedup 1.0000x reference)
//
#include <hip/hip_runtime.h>

#define SCALE 0.17677669529663687f  // 1/sqrt(32)

// ---------- LayerNorm: one wave per token (256 dims, 4 per lane) ----------
__global__ __launch_bounds__(256) void ln_kernel(const float* __restrict__ in,
    const float* __restrict__ g, const float* __restrict__ bb,
    float* __restrict__ out, int ntok) {
  int wid = (blockIdx.x * 256 + threadIdx.x) >> 6;
  int lane = threadIdx.x & 63;
  if (wid >= ntok) return;
  const float4 v = *(const float4*)(in + (size_t)wid * 256 + lane * 4);
  float s = v.x + v.y + v.z + v.w;
  #pragma unroll
  for (int off = 32; off; off >>= 1) s += __shfl_down(s, off);
  float mean = __shfl(s, 0) * (1.0f / 256.0f);
  float dx = v.x - mean, dy = v.y - mean, dz = v.z - mean, dw = v.w - mean;
  float vs = dx * dx + dy * dy + dz * dz + dw * dw;
  #pragma unroll
  for (int off = 32; off; off >>= 1) vs += __shfl_down(vs, off);
  float rstd = rsqrtf(__shfl(vs, 0) * (1.0f / 256.0f) + 1e-5f);
  const float4 gg = *(const float4*)(g + lane * 4);
  const float4 bv = *(const float4*)(bb + lane * 4);
  float4 o;
  o.x = dx * rstd * gg.x + bv.x;
  o.y = dy * rstd * gg.y + bv.y;
  o.z = dz * rstd * gg.z + bv.z;
  o.w = dw * rstd * gg.w + bv.w;
  *(float4*)(out + (size_t)wid * 256 + lane * 4) = o;
}

// ---------- 2x2 mean pool over H,W: x[4,64,64,256] -> xr[4,32,32,256] ----------
__global__ __launch_bounds__(256) void pool_kernel(const float* __restrict__ x,
    float* __restrict__ xr) {
  int idx = blockIdx.x * 256 + threadIdx.x;   // 0 .. 4096*64-1
  int t = idx >> 6, c4 = (idx & 63) << 2;
  int b = t >> 10, rem = t & 1023;
  int i = rem >> 5, j = rem & 31;
  size_t base = ((size_t)b * 4096 + i * 128 + j * 2) * 256 + c4;
  float4 a0 = *(const float4*)(x + base);
  float4 a1 = *(const float4*)(x + base + 256);
  float4 a2 = *(const float4*)(x + base + 16384);
  float4 a3 = *(const float4*)(x + base + 16640);
  float4 o;
  o.x = 0.25f * (a0.x + a1.x + a2.x + a3.x);
  o.y = 0.25f * (a0.y + a1.y + a2.y + a3.y);
  o.z = 0.25f * (a0.z + a1.z + a2.z + a3.z);
  o.w = 0.25f * (a0.w + a1.w + a2.w + a3.w);
  *(float4*)(xr + (size_t)t * 256 + c4) = o;
}

// ---------- C[M,256] = A[M,256] @ W[256,256] (+bias) (+resid), 64x64 tiles ----------
__global__ __launch_bounds__(256) void gemm256(const float* __restrict__ A,
    const float* __restrict__ W, const float* __restrict__ bias,
    const float* __restrict__ resid, float* __restrict__ C, int M) {
  __shared__ float As[16][68];   // [k][m] transposed
  __shared__ float Bs[16][68];   // [k][n]
  const int tid = threadIdx.x;
  const int tx = tid & 15, ty = tid >> 4;
  const int row0 = blockIdx.x * 64, col0 = blockIdx.y * 64;
  float acc[4][4] = {};
  const int lr = tid >> 2;            // 0..63  A row
  const int lc = (tid & 3) << 2;      // 0,4,8,12  A k-col
  const int wr = tid >> 4;            // 0..15  W k-row
  const int wc = (tid & 15) << 2;     // W col
  for (int k0 = 0; k0 < 256; k0 += 16) {
    float4 av = *(const float4*)(A + (size_t)(row0 + lr) * 256 + k0 + lc);
    As[lc + 0][lr] = av.x; As[lc + 1][lr] = av.y;
    As[lc + 2][lr] = av.z; As[lc + 3][lr] = av.w;
    *(float4*)&Bs[wr][wc] = *(const float4*)(W + (size_t)(k0 + wr) * 256 + col0 + wc);
    __syncthreads();
    #pragma unroll
    for (int k = 0; k < 16; ++k) {
      float4 a4 = *(const float4*)&As[k][ty << 2];
      float4 b4 = *(const float4*)&Bs[k][tx << 2];
      float a[4] = {a4.x, a4.y, a4.z, a4.w};
      float b[4] = {b4.x, b4.y, b4.z, b4.w};
      #pragma unroll
      for (int i = 0; i < 4; ++i)
        #pragma unroll
        for (int j = 0; j < 4; ++j) acc[i][j] += a[i] * b[j];
    }
    __syncthreads();
  }
  #pragma unroll
  for (int i = 0; i < 4; ++i) {
    int row = row0 + (ty << 2) + i;
    int col = col0 + (tx << 2);
    float4 o = {acc[i][0], acc[i][1], acc[i][2], acc[i][3]};
    if (bias) {
      o.x += bias[col]; o.y += bias[col + 1]; o.z += bias[col + 2]; o.w += bias[col + 3];
    }
    if (resid) {
      float4 r = *(const float4*)(resid + (size_t)row * 256 + col);
      o.x += r.x; o.y += r.y; o.z += r.z; o.w += r.w;
    }
    *(float4*)(C + (size_t)row * 256 + col) = o;
  }
}

// ---------- raw scores: attn[bh, q, j] = SCALE * q_row . k_row ----------
__global__ __launch_bounds__(256) void qk_kernel(const float* __restrict__ q,
    const float* __restrict__ k, float* __restrict__ attn) {
  __shared__ float Qt[32][64];     // [d][row]
  __shared__ float Kt[32][136];    // [d][col]
  const int tid = threadIdx.x;
  const int bh = blockIdx.z;
  const int b = bh >> 3, h = bh & 7;
  const int q0 = blockIdx.x * 64;
  const int j0 = blockIdx.y * 128;
  #pragma unroll
  for (int it = 0; it < 2; ++it) {
    int idx = tid + it * 256;               // 512 float4s
    int r = idx >> 3, c4 = (idx & 7) << 2;
    float4 v = *(const float4*)(q + ((size_t)(b * 4096 + q0 + r)) * 256 + h * 32 + c4);
    Qt[c4 + 0][r] = v.x; Qt[c4 + 1][r] = v.y; Qt[c4 + 2][r] = v.z; Qt[c4 + 3][r] = v.w;
  }
  #pragma unroll
  for (int it = 0; it < 4; ++it) {
    int idx = tid + it * 256;               // 1024 float4s
    int r = idx >> 3, c4 = (idx & 7) << 2;
    float4 v = *(const float4*)(k + ((size_t)(b * 1024 + j0 + r)) * 256 + h * 32 + c4);
    Kt[c4 + 0][r] = v.x; Kt[c4 + 1][r] = v.y; Kt[c4 + 2][r] = v.z; Kt[c4 + 3][r] = v.w;
  }
  __syncthreads();
  const int tx = tid & 15, ty = tid >> 4;
  float acc[4][8] = {};
  #pragma unroll
  for (int kk = 0; kk < 32; ++kk) {
    float4 a4 = *(const float4*)&Qt[kk][ty << 2];
    float4 b0 = *(const float4*)&Kt[kk][tx << 2];
    float4 b1 = *(const float4*)&Kt[kk][64 + (tx << 2)];
    float a[4] = {a4.x, a4.y, a4.z, a4.w};
    float bb[8] = {b0.x, b0.y, b0.z, b0.w, b1.x, b1.y, b1.z, b1.w};
    #pragma unroll
    for (int i = 0; i < 4; ++i)
      #pragma unroll
      for (int j = 0; j < 8; ++j) acc[i][j] += a[i] * bb[j];
  }
  #pragma unroll
  for (int i = 0; i < 4; ++i) {
    size_t row = (size_t)bh * 4096 + q0 + (ty << 2) + i;
    float4 o0 = {acc[i][0] * SCALE, acc[i][1] * SCALE, acc[i][2] * SCALE, acc[i][3] * SCALE};
    float4 o1 = {acc[i][4] * SCALE, acc[i][5] * SCALE, acc[i][6] * SCALE, acc[i][7] * SCALE};
    *(float4*)(attn + row * 1024 + j0 + (tx << 2)) = o0;
    *(float4*)(attn + row * 1024 + j0 + 64 + (tx << 2)) = o1;
  }
}

// ---------- in-place row softmax over 1024 cols, one wave per row ----------
__global__ __launch_bounds__(256) void softmax_kernel(float* __restrict__ attn) {
  int wid = (blockIdx.x * 256 + threadIdx.x) >> 6;   // 0..131071
  int lane = threadIdx.x & 63;
  float* row = attn + (size_t)wid * 1024;
  float4 v[4];
  float m = -1e30f;
  #pragma unroll
  for (int i = 0; i < 4; ++i) {
    v[i] = *(const float4*)(row + i * 256 + lane * 4);
    m = fmaxf(m, fmaxf(fmaxf(v[i].x, v[i].y), fmaxf(v[i].z, v[i].w)));
  }
  #pragma unroll
  for (int off = 32; off; off >>= 1) m = fmaxf(m, __shfl_down(m, off));
  m = __shfl(m, 0);
  float s = 0.0f;
  #pragma unroll
  for (int i = 0; i < 4; ++i) {
    v[i].x = __expf(v[i].x - m); v[i].y = __expf(v[i].y - m);
    v[i].z = __expf(v[i].z - m); v[i].w = __expf(v[i].w - m);
    s += v[i].x + v[i].y + v[i].z + v[i].w;
  }
  #pragma unroll
  for (int off = 32; off; off >>= 1) s += __shfl_down(s, off);
  float inv = 1.0f / __shfl(s, 0);
  #pragma unroll
  for (int i = 0; i < 4; ++i) {
    v[i].x *= inv; v[i].y *= inv; v[i].z *= inv; v[i].w *= inv;
    *(float4*)(row + i * 256 + lane * 4) = v[i];
  }
}

// ---------- out[b, n, h*32+d] = attn[bh] @ v[bh] ----------
__global__ __launch_bounds__(256) void pv_kernel(const float* __restrict__ attn,
    const float* __restrict__ v, float* __restrict__ out) {
  __shared__ float Vt[128][32];
  __shared__ float As[32][129];
  const int tid = threadIdx.x;
  const int bh = blockIdx.y, b = bh >> 3, h = bh & 7;
  const int n0 = blockIdx.x * 32;
  const int tx = tid & 7, ty = tid >> 3;   // d-group, row
  float acc[4] = {};
  for (int j0 = 0; j0 < 1024; j0 += 128) {
    __syncthreads();
    #pragma unroll
    for (int it = 0; it < 4; ++it) {
      int idx = tid + it * 256;             // 1024 float4s of V chunk
      int r = idx >> 3, c4 = (idx & 7) << 2;
      *(float4*)&Vt[r][c4] =
          *(const float4*)(v + ((size_t)(b * 1024 + j0 + r)) * 256 + h * 32 + c4);
    }
    #pragma unroll
    for (int it = 0; it < 4; ++it) {
      int idx = tid + it * 256;             // 1024 float4s of attn chunk
      int r = idx >> 5, c4 = (idx & 31) << 2;
      float4 a = *(const float4*)(attn + ((size_t)bh * 4096 + n0 + r) * 1024 + j0 + c4);
      As[r][c4 + 0] = a.x; As[r][c4 + 1] = a.y; As[r][c4 + 2] = a.z; As[r][c4 + 3] = a.w;
    }
    __syncthreads();
    #pragma unroll 16
    for (int jj = 0; jj < 128; ++jj) {
      float a = As[ty][jj];
      float4 vv = *(const float4*)&Vt[jj][tx << 2];
      acc[0] += a * vv.x; acc[1] += a * vv.y; acc[2] += a * vv.z; acc[3] += a * vv.w;
    }
  }
  float4 o = {acc[0], acc[1], acc[2], acc[3]};
  *(float4*)(out + ((size_t)b * 4096 + n0 + ty) * 256 + h * 32 + (tx << 2)) = o;
}

extern "C" void kernel_launch(void* const* d_in, const int* in_sizes, int n_in,
                              void* d_out, int out_size, void* d_ws, size_t ws_size,
                              hipStream_t stream) {
  (void)in_sizes; (void)n_in; (void)out_size; (void)ws_size;
  const float* x     = (const float*)d_in[0];
  const float* ln1_g = (const float*)d_in[2];
  const float* ln1_b = (const float*)d_in[3];
  const float* Wq    = (const float*)d_in[4];
  const float* bq    = (const float*)d_in[5];
  const float* Wk    = (const float*)d_in[6];
  const float* bk    = (const float*)d_in[7];
  const float* Wv    = (const float*)d_in[8];
  const float* bv    = (const float*)d_in[9];
  const float* Wmean = (const float*)d_in[10];
  const float* ln2_g = (const float*)d_in[11];
  const float* ln2_b = (const float*)d_in[12];
  const float* Wo    = (const float*)d_in[13];
  const float* bo    = (const float*)d_in[14];

  float* out  = (float*)d_out;          // [16384, 256]
  float* attn = out + 4194304;          // [32, 4096, 1024]
  float* ws   = (float*)d_ws;
  float* xn   = ws;                     // 4194304  (x_norm; later reused as attn-out)
  float* q    = ws + 4194304;           // 4194304
  float* xr   = ws + 8388608;           // 1048576  (pool; later x_red_norm)
  float* xrm  = ws + 9437184;           // 1048576
  float* kbuf = ws + 10485760;          // 1048576
  float* vbuf = ws + 11534336;          // 1048576
  float* oat  = ws;                     // reuse xn

  ln_kernel<<<4096, 256, 0, stream>>>(x, ln1_g, ln1_b, xn, 16384);
  gemm256<<<dim3(256, 4), 256, 0, stream>>>(xn, Wq, bq, nullptr, q, 16384);
  pool_kernel<<<1024, 256, 0, stream>>>(x, xr);
  gemm256<<<dim3(64, 4), 256, 0, stream>>>(xr, Wmean, nullptr, nullptr, xrm, 4096);
  ln_kernel<<<1024, 256, 0, stream>>>(xrm, ln2_g, ln2_b, xr, 4096);
  gemm256<<<dim3(64, 4), 256, 0, stream>>>(xr, Wk, bk, nullptr, kbuf, 4096);
  gemm256<<<dim3(64, 4), 256, 0, stream>>>(xr, Wv, bv, nullptr, vbuf, 4096);
  qk_kernel<<<dim3(64, 8, 32), 256, 0, stream>>>(q, kbuf, attn);
  softmax_kernel<<<32768, 256, 0, stream>>>(attn);
  pv_kernel<<<dim3(128, 32), 256, 0, stream>>>(attn, vbuf, oat);
  gemm256<<<dim3(256, 4), 256, 0, stream>>>(oat, Wo, bo, x, out, 16384);
}

// Round 2
// 783.659 us; speedup vs baseline: 1.4797x; 1.4797x over previous
//
#include <hip/hip_runtime.h>

typedef __bf16 bf16x8 __attribute__((ext_vector_type(8)));
typedef __bf16 bf16x4 __attribute__((ext_vector_type(4)));
typedef float f32x4 __attribute__((ext_vector_type(4)));

#define SCALE 0.17677669529663687f  // 1/sqrt(32)

// ---------- weight cast+transpose: Wt[n][k] bf16 = W[k][n] fp32 ----------
__global__ __launch_bounds__(256) void castw_kernel(const float* __restrict__ W,
    __bf16* __restrict__ Wt) {
  int id = blockIdx.x * 256 + threadIdx.x;   // 65536 ids
  int kk = id >> 8, n = id & 255;
  Wt[n * 256 + kk] = (__bf16)W[id];
}

// ---------- LayerNorm fp32-in -> bf16-out, one wave per token ----------
__global__ __launch_bounds__(256) void ln_fp32_kernel(const float* __restrict__ in,
    const float* __restrict__ g, const float* __restrict__ bb,
    __bf16* __restrict__ out) {
  int wid = (blockIdx.x * 256 + threadIdx.x) >> 6;
  int lane = threadIdx.x & 63;
  const float4 v = *(const float4*)(in + (size_t)wid * 256 + lane * 4);
  float s = v.x + v.y + v.z + v.w;
  #pragma unroll
  for (int off = 32; off; off >>= 1) s += __shfl_down(s, off);
  float mean = __shfl(s, 0) * (1.0f / 256.0f);
  float dx = v.x - mean, dy = v.y - mean, dz = v.z - mean, dw = v.w - mean;
  float vs = dx * dx + dy * dy + dz * dz + dw * dw;
  #pragma unroll
  for (int off = 32; off; off >>= 1) vs += __shfl_down(vs, off);
  float rstd = rsqrtf(__shfl(vs, 0) * (1.0f / 256.0f) + 1e-5f);
  const float4 gg = *(const float4*)(g + lane * 4);
  const float4 bv = *(const float4*)(bb + lane * 4);
  bf16x4 o4;
  o4[0] = (__bf16)(dx * rstd * gg.x + bv.x);
  o4[1] = (__bf16)(dy * rstd * gg.y + bv.y);
  o4[2] = (__bf16)(dz * rstd * gg.z + bv.z);
  o4[3] = (__bf16)(dw * rstd * gg.w + bv.w);
  *(bf16x4*)(out + (size_t)wid * 256 + lane * 4) = o4;
}

// ---------- LayerNorm bf16-in -> bf16-out ----------
__global__ __launch_bounds__(256) void ln_bf16_kernel(const __bf16* __restrict__ in,
    const float* __restrict__ g, const float* __restrict__ bb,
    __bf16* __restrict__ out) {
  int wid = (blockIdx.x * 256 + threadIdx.x) >> 6;
  int lane = threadIdx.x & 63;
  bf16x4 iv = *(const bf16x4*)(in + (size_t)wid * 256 + lane * 4);
  float vx = (float)iv[0], vy = (float)iv[1], vz = (float)iv[2], vw = (float)iv[3];
  float s = vx + vy + vz + vw;
  #pragma unroll
  for (int off = 32; off; off >>= 1) s += __shfl_down(s, off);
  float mean = __shfl(s, 0) * (1.0f / 256.0f);
  float dx = vx - mean, dy = vy - mean, dz = vz - mean, dw = vw - mean;
  float vs = dx * dx + dy * dy + dz * dz + dw * dw;
  #pragma unroll
  for (int off = 32; off; off >>= 1) vs += __shfl_down(vs, off);
  float rstd = rsqrtf(__shfl(vs, 0) * (1.0f / 256.0f) + 1e-5f);
  const float4 gg = *(const float4*)(g + lane * 4);
  const float4 bv = *(const float4*)(bb + lane * 4);
  bf16x4 o4;
  o4[0] = (__bf16)(dx * rstd * gg.x + bv.x);
  o4[1] = (__bf16)(dy * rstd * gg.y + bv.y);
  o4[2] = (__bf16)(dz * rstd * gg.z + bv.z);
  o4[3] = (__bf16)(dw * rstd * gg.w + bv.w);
  *(bf16x4*)(out + (size_t)wid * 256 + lane * 4) = o4;
}

// ---------- 2x2 mean pool fp32 -> bf16 ----------
__global__ __launch_bounds__(256) void pool_kernel(const float* __restrict__ x,
    __bf16* __restrict__ xp) {
  int idx = blockIdx.x * 256 + threadIdx.x;   // 4096*64
  int t = idx >> 6, c4 = (idx & 63) << 2;
  int b = t >> 10, rem = t & 1023;
  int i = rem >> 5, j = rem & 31;
  size_t base = ((size_t)b * 4096 + i * 128 + j * 2) * 256 + c4;
  float4 a0 = *(const float4*)(x + base);
  float4 a1 = *(const float4*)(x + base + 256);
  float4 a2 = *(const float4*)(x + base + 16384);
  float4 a3 = *(const float4*)(x + base + 16640);
  bf16x4 o4;
  o4[0] = (__bf16)(0.25f * (a0.x + a1.x + a2.x + a3.x));
  o4[1] = (__bf16)(0.25f * (a0.y + a1.y + a2.y + a3.y));
  o4[2] = (__bf16)(0.25f * (a0.z + a1.z + a2.z + a3.z));
  o4[3] = (__bf16)(0.25f * (a0.w + a1.w + a2.w + a3.w));
  *(bf16x4*)(xp + (size_t)t * 256 + c4) = o4;
}

// ---------- MFMA GEMM: C[M,256] = A[M,256] @ W (Wt[n][k] bf16) + bias ----------
// mode 0: C bf16 natural [M][256]
// mode 1: C bf16 transposed-per-batch vT[(b*256+n)*1024 + tloc]  (M = 4096)
// mode 2: C fp32 [M][256] + resid
__global__ __launch_bounds__(256) void gemm_mfma(
    const __bf16* __restrict__ A, const __bf16* __restrict__ Wt,
    const float* __restrict__ bias, const float* __restrict__ resid,
    void* __restrict__ Cout, int mode) {
  const int tid = threadIdx.x;
  const int w = tid >> 6, l = tid & 63;
  const int col = l & 15, quad = l >> 4;
  const int row0 = blockIdx.x * 64 + w * 16;
  const int col0 = blockIdx.y * 64;
  f32x4 acc[4] = {{0.f,0.f,0.f,0.f},{0.f,0.f,0.f,0.f},{0.f,0.f,0.f,0.f},{0.f,0.f,0.f,0.f}};
  const __bf16* ap = A + (size_t)(row0 + col) * 256 + quad * 8;
  #pragma unroll
  for (int ks = 0; ks < 8; ++ks) {
    bf16x8 af = *(const bf16x8*)(ap + ks * 32);
    #pragma unroll
    for (int n = 0; n < 4; ++n) {
      bf16x8 bf = *(const bf16x8*)(Wt + (size_t)(col0 + n * 16 + col) * 256 + ks * 32 + quad * 8);
      acc[n] = __builtin_amdgcn_mfma_f32_16x16x32_bf16(af, bf, acc[n], 0, 0, 0);
    }
  }
  const int rbase = row0 + quad * 4;
  #pragma unroll
  for (int n = 0; n < 4; ++n) {
    const int cc = col0 + n * 16 + col;
    const float bv = bias ? bias[cc] : 0.0f;
    if (mode == 0) {
      __bf16* C = (__bf16*)Cout;
      #pragma unroll
      for (int r = 0; r < 4; ++r)
        C[(size_t)(rbase + r) * 256 + cc] = (__bf16)(acc[n][r] + bv);
    } else if (mode == 1) {
      __bf16* C = (__bf16*)Cout;
      const int bb2 = rbase >> 10, tl = rbase & 1023;
      bf16x4 o4;
      #pragma unroll
      for (int r = 0; r < 4; ++r) o4[r] = (__bf16)(acc[n][r] + bv);
      *(bf16x4*)(C + ((size_t)(bb2 * 256 + cc)) * 1024 + tl) = o4;
    } else {
      float* C = (float*)Cout;
      #pragma unroll
      for (int r = 0; r < 4; ++r) {
        size_t off = (size_t)(rbase + r) * 256 + cc;
        C[off] = acc[n][r] + bv + resid[off];
      }
    }
  }
}

// ---------- fused attention: QK^T -> softmax -> (attn write) -> PV ----------
// block = (q-tile of 16 rows, bh); 256 threads = 4 waves.
// LDS score tile Ss[16][1024] fp32, bank-swizzled.
__device__ __forceinline__ int swz(int row, int c) {
  return row * 1024 + (c ^ ((row & 3) << 3));
}

__global__ __launch_bounds__(256) void attn_fused(
    const __bf16* __restrict__ q, const __bf16* __restrict__ kb,
    const __bf16* __restrict__ vT, float* __restrict__ attn,
    __bf16* __restrict__ oat) {
  __shared__ float Ss[16 * 1024];
  const int tid = threadIdx.x;
  const int w = tid >> 6, l = tid & 63;
  const int col = l & 15, quad = l >> 4;
  const int bh = blockIdx.y, b = bh >> 3, h = bh & 7;
  const int q0 = blockIdx.x * 16;

  // Phase 1: S = SCALE * Q K^T for this wave's 256-col strip
  bf16x8 qf = *(const bf16x8*)(q + ((size_t)(b * 4096 + q0 + col)) * 256 + h * 32 + quad * 8);
  const __bf16* kbase = kb + ((size_t)(b * 1024 + col)) * 256 + h * 32 + quad * 8;
  #pragma unroll 4
  for (int t = 0; t < 16; ++t) {
    int j0 = w * 256 + t * 16;
    bf16x8 kf = *(const bf16x8*)(kbase + (size_t)j0 * 256);
    f32x4 c = {0.f, 0.f, 0.f, 0.f};
    c = __builtin_amdgcn_mfma_f32_16x16x32_bf16(qf, kf, c, 0, 0, 0);
    #pragma unroll
    for (int r = 0; r < 4; ++r)
      Ss[swz(quad * 4 + r, j0 + col)] = c[r] * SCALE;
  }
  __syncthreads();

  // Phase 2: softmax rows w*4 .. w*4+3; write attn (fp32) + probs back to LDS
  #pragma unroll
  for (int rr = 0; rr < 4; ++rr) {
    int row = w * 4 + rr;
    float4 v4[4];
    float m = -1e30f;
    #pragma unroll
    for (int i = 0; i < 4; ++i) {
      v4[i] = *(const float4*)(&Ss[swz(row, i * 256 + l * 4)]);
      m = fmaxf(m, fmaxf(fmaxf(v4[i].x, v4[i].y), fmaxf(v4[i].z, v4[i].w)));
    }
    #pragma unroll
    for (int off = 32; off; off >>= 1) m = fmaxf(m, __shfl_down(m, off));
    m = __shfl(m, 0);
    float s = 0.f;
    #pragma unroll
    for (int i = 0; i < 4; ++i) {
      v4[i].x = __expf(v4[i].x - m); v4[i].y = __expf(v4[i].y - m);
      v4[i].z = __expf(v4[i].z - m); v4[i].w = __expf(v4[i].w - m);
      s += v4[i].x + v4[i].y + v4[i].z + v4[i].w;
    }
    #pragma unroll
    for (int off = 32; off; off >>= 1) s += __shfl_down(s, off);
    float inv = 1.0f / __shfl(s, 0);
    float* arow = attn + ((size_t)bh * 4096 + q0 + row) * 1024;
    #pragma unroll
    for (int i = 0; i < 4; ++i) {
      v4[i].x *= inv; v4[i].y *= inv; v4[i].z *= inv; v4[i].w *= inv;
      *(float4*)(arow + i * 256 + l * 4) = v4[i];
      *(float4*)(&Ss[swz(row, i * 256 + l * 4)]) = v4[i];
    }
  }
  __syncthreads();

  // Phase 3: partial PV over this wave's 256-col strip (two 16-wide d tiles)
  f32x4 a0 = {0.f, 0.f, 0.f, 0.f}, a1 = {0.f, 0.f, 0.f, 0.f};
  const __bf16* v0p = vT + ((size_t)(b * 256 + h * 32 + col)) * 1024;
  const __bf16* v1p = v0p + 16 * 1024;
  #pragma unroll 2
  for (int s8 = 0; s8 < 8; ++s8) {
    int k0 = w * 256 + s8 * 32;
    int base = swz(col, k0 + quad * 8);
    f32x4 p0 = *(const f32x4*)(&Ss[base]);
    f32x4 p1 = *(const f32x4*)(&Ss[base + 4]);
    bf16x8 af;
    af[0] = (__bf16)p0[0]; af[1] = (__bf16)p0[1]; af[2] = (__bf16)p0[2]; af[3] = (__bf16)p0[3];
    af[4] = (__bf16)p1[0]; af[5] = (__bf16)p1[1]; af[6] = (__bf16)p1[2]; af[7] = (__bf16)p1[3];
    bf16x8 b0 = *(const bf16x8*)(v0p + k0 + quad * 8);
    bf16x8 b1 = *(const bf16x8*)(v1p + k0 + quad * 8);
    a0 = __builtin_amdgcn_mfma_f32_16x16x32_bf16(af, b0, a0, 0, 0, 0);
    a1 = __builtin_amdgcn_mfma_f32_16x16x32_bf16(af, b1, a1, 0, 0, 0);
  }
  __syncthreads();

  // cross-wave reduce via LDS (reuse Ss): part[w][16][32]
  float* part = Ss;
  #pragma unroll
  for (int r = 0; r < 4; ++r) {
    part[(w * 16 + quad * 4 + r) * 32 + col] = a0[r];
    part[(w * 16 + quad * 4 + r) * 32 + 16 + col] = a1[r];
  }
  __syncthreads();
  int idx = tid;
  #pragma unroll
  for (int it = 0; it < 2; ++it, idx += 256) {
    int row = idx >> 5, d = idx & 31;
    float sum = part[row * 32 + d] + part[(16 + row) * 32 + d]
              + part[(32 + row) * 32 + d] + part[(48 + row) * 32 + d];
    oat[((size_t)(b * 4096 + q0 + row)) * 256 + h * 32 + d] = (__bf16)sum;
  }
}

extern "C" void kernel_launch(void* const* d_in, const int* in_sizes, int n_in,
                              void* d_out, int out_size, void* d_ws, size_t ws_size,
                              hipStream_t stream) {
  (void)in_sizes; (void)n_in; (void)out_size; (void)ws_size;
  const float* x     = (const float*)d_in[0];
  const float* ln1_g = (const float*)d_in[2];
  const float* ln1_b = (const float*)d_in[3];
  const float* Wq    = (const float*)d_in[4];
  const float* bq    = (const float*)d_in[5];
  const float* Wk    = (const float*)d_in[6];
  const float* bk    = (const float*)d_in[7];
  const float* Wv    = (const float*)d_in[8];
  const float* bv    = (const float*)d_in[9];
  const float* Wmean = (const float*)d_in[10];
  const float* ln2_g = (const float*)d_in[11];
  const float* ln2_b = (const float*)d_in[12];
  const float* Wo    = (const float*)d_in[13];
  const float* bo    = (const float*)d_in[14];

  float* out  = (float*)d_out;           // [16384, 256] fp32
  float* attn = out + 4194304;           // [32, 4096, 1024] fp32

  __bf16* w0   = (__bf16*)d_ws;
  __bf16* xn   = w0;                     // 4,194,304
  __bf16* qb   = w0 + 4194304;           // 4,194,304
  __bf16* oat  = w0 + 8388608;           // 4,194,304
  __bf16* xp   = w0 + 12582912;          // 1,048,576
  __bf16* xrm  = w0 + 13631488;          // 1,048,576
  __bf16* xr   = w0 + 14680064;          // 1,048,576
  __bf16* kbuf = w0 + 15728640;          // 1,048,576
  __bf16* vTb  = w0 + 16777216;          // 1,048,576
  __bf16* WtQ  = w0 + 17825792;          // 5 x 65,536
  __bf16* WtK  = WtQ + 65536;
  __bf16* WtV  = WtK + 65536;
  __bf16* WtM  = WtV + 65536;
  __bf16* WtO  = WtM + 65536;

  castw_kernel<<<256, 256, 0, stream>>>(Wq, WtQ);
  castw_kernel<<<256, 256, 0, stream>>>(Wk, WtK);
  castw_kernel<<<256, 256, 0, stream>>>(Wv, WtV);
  castw_kernel<<<256, 256, 0, stream>>>(Wmean, WtM);
  castw_kernel<<<256, 256, 0, stream>>>(Wo, WtO);

  ln_fp32_kernel<<<4096, 256, 0, stream>>>(x, ln1_g, ln1_b, xn);
  gemm_mfma<<<dim3(256, 4), 256, 0, stream>>>(xn, WtQ, bq, nullptr, qb, 0);
  pool_kernel<<<1024, 256, 0, stream>>>(x, xp);
  gemm_mfma<<<dim3(64, 4), 256, 0, stream>>>(xp, WtM, nullptr, nullptr, xrm, 0);
  ln_bf16_kernel<<<1024, 256, 0, stream>>>(xrm, ln2_g, ln2_b, xr);
  gemm_mfma<<<dim3(64, 4), 256, 0, stream>>>(xr, WtK, bk, nullptr, kbuf, 0);
  gemm_mfma<<<dim3(64, 4), 256, 0, stream>>>(xr, WtV, bv, nullptr, vTb, 1);
  attn_fused<<<dim3(256, 32), 256, 0, stream>>>(qb, kbuf, vTb, attn, oat);
  gemm_mfma<<<dim3(256, 4), 256, 0, stream>>>(oat, WtO, bo, x, (void*)out, 2);
}